// Round 1
// baseline (519.682 us; speedup 1.0000x reference)
//
#include <hip/hip_runtime.h>

#define HW   4096      // 64*64
#define CDIM 64
#define KCB  1024
#define NPTS 131072    // 32*4096
#define NELM 8388608   // NPTS*CDIM

// ws layout: ws[0..1023] = e_sq (sum of squares per code row), ws[1024] = loss accumulator
__global__ void vq_prep(const float* __restrict__ cb, float* __restrict__ ws) {
    int k = blockIdx.x * blockDim.x + threadIdx.x;
    if (k == 0) ws[KCB] = 0.0f;          // zero the accumulator (harness poisons ws)
    if (k < KCB) {
        const float* row = cb + k * CDIM;
        float s = 0.0f;
        #pragma unroll
        for (int c = 0; c < CDIM; ++c) s = fmaf(row[c], row[c], s);
        ws[k] = s;
    }
}

__global__ __launch_bounds__(256)
void vq_main(const float* __restrict__ x,
             const float* __restrict__ cb,
             const float* __restrict__ esq,
             float* __restrict__ zq,
             float* __restrict__ accum) {
    const int p  = threadIdx.x;
    const int n  = blockIdx.x * 256 + p;     // global point index
    const int b  = n >> 12;                  // n / HW
    const int hw = n & (HW - 1);

    // x[b][c][hw]: consecutive threads -> consecutive hw -> coalesced per channel
    const float* xp = x + (size_t)b * CDIM * HW + hw;
    float xv[CDIM];
    #pragma unroll
    for (int c = 0; c < CDIM; ++c) xv[c] = xp[(size_t)c * HW];

    // argmin_k  e_sq[k] - 2 * dot(x, e_k)   (x_sq is a per-point constant)
    float best = 3.4e38f;
    int   bidx = 0;
    for (int k = 0; k < KCB; ++k) {
        const float* ek = cb + k * CDIM;     // wave-uniform -> scalar loads
        float a0 = 0.f, a1 = 0.f, a2 = 0.f, a3 = 0.f;
        #pragma unroll
        for (int c = 0; c < CDIM; c += 4) {
            a0 = fmaf(xv[c + 0], ek[c + 0], a0);
            a1 = fmaf(xv[c + 1], ek[c + 1], a1);
            a2 = fmaf(xv[c + 2], ek[c + 2], a2);
            a3 = fmaf(xv[c + 3], ek[c + 3], a3);
        }
        float dot = (a0 + a1) + (a2 + a3);
        float d   = fmaf(-2.0f, dot, esq[k]);
        if (d < best) { best = d; bidx = k; }
    }

    // Epilogue: gather winning code row once (L2-resident codebook),
    // fuse mse partial + coalesced z_q store (stride-HW rows, contiguous in hw).
    const float* crow = cb + (size_t)bidx * CDIM;
    float*       zp   = zq + (size_t)b * CDIM * HW + hw;
    float se = 0.0f;
    #pragma unroll 8
    for (int c = 0; c < CDIM; ++c) {
        float ev  = crow[c];
        float dxc = xv[c] - ev;
        se = fmaf(dxc, dxc, se);
        zp[(size_t)c * HW] = ev;
    }

    // Block reduction of squared-error partials -> one atomic per block
    #pragma unroll
    for (int off = 32; off > 0; off >>= 1) se += __shfl_down(se, off, 64);
    __shared__ float wsum[4];
    if ((p & 63) == 0) wsum[p >> 6] = se;
    __syncthreads();
    if (p == 0) {
        float t = wsum[0] + wsum[1] + wsum[2] + wsum[3];
        atomicAdd(accum, t);
    }
}

__global__ void vq_final(const float* __restrict__ accum, float* __restrict__ out_loss) {
    float mse = accum[0] * (1.0f / (float)NELM);
    out_loss[0] = 1.25f * mse;   // mse + commitment_cost * mse
}

extern "C" void kernel_launch(void* const* d_in, const int* in_sizes, int n_in,
                              void* d_out, int out_size, void* d_ws, size_t ws_size,
                              hipStream_t stream) {
    const float* x  = (const float*)d_in[0];
    const float* cb = (const float*)d_in[1];
    float* esq   = (float*)d_ws;        // 1024 floats
    float* accum = esq + KCB;           // 1 float
    float* zq    = (float*)d_out;       // 8388608 floats
    float* loss  = zq + NELM;           // 1 float

    vq_prep <<<4,   256, 0, stream>>>(cb, esq);
    vq_main <<<512, 256, 0, stream>>>(x, cb, esq, zq, accum);
    vq_final<<<1,   1,   0, stream>>>(accum, loss);
}

// Round 2
// 121.451 us; speedup vs baseline: 4.2789x; 4.2789x over previous
//
#include <hip/hip_runtime.h>

#define HW    4096
#define CDIM  64
#define KCB   1024
#define NELM  8388608

typedef __attribute__((ext_vector_type(8))) short  short8;
typedef __attribute__((ext_vector_type(4))) float  float4v;

__device__ inline unsigned short f2bf(float v) {
    unsigned u = __builtin_bit_cast(unsigned, v);
    unsigned r = u + 0x7FFF + ((u >> 16) & 1);   // RNE
    return (unsigned short)(r >> 16);
}

// ws: [0..1023] e_sq fp32, [1024] loss accum, [2048..] bf16 codebook in B-frag order
__global__ void vq_prep(const float* __restrict__ cb, float* __restrict__ esq,
                        float* __restrict__ accum, unsigned short* __restrict__ cbB) {
    int u = blockIdx.x * 256 + threadIdx.x;      // 0..8191
    if (u == 0) *accum = 0.0f;
    if (u < KCB) {
        const float* row = cb + u * CDIM;
        float s = 0.0f;
        #pragma unroll
        for (int c = 0; c < CDIM; ++c) s = fmaf(row[c], row[c], s);
        esq[u] = s;
    }
    // B-frag order: lane l of code-tile t, frag f reads B[k=f*32+(l>>4)*8+j][n=t*16+(l&15)]
    int k = u >> 3, s7 = u & 7;                  // code, 8-channel segment
    const float* src = cb + k * CDIM + s7 * 8;
    unsigned short tmp[8];
    #pragma unroll
    for (int j = 0; j < 8; ++j) tmp[j] = f2bf(src[j]);
    int t = k >> 4, n = k & 15, f = s7 >> 2, q = s7 & 3;
    int dst = (((t * 2 + f) * 64) + q * 16 + n) * 8;
    *(short8*)(cbB + dst) = *(short8*)tmp;
}

__global__ __launch_bounds__(256)
void vq_main(const float* __restrict__ x,
             const float* __restrict__ cb,
             const float* __restrict__ esq,
             const unsigned short* __restrict__ cbB,
             float* __restrict__ zq,
             float* __restrict__ accum) {
    __shared__ unsigned short abf[128 * 72];   // -2x bf16, A-frag layout, stride 72
    __shared__ float xsqp[256];
    __shared__ float dbl[128];
    __shared__ int   idxl[128];
    __shared__ float part[2];

    const int t  = threadIdx.x;
    const int n0 = blockIdx.x * 128;
    const int b  = n0 >> 12;
    const int hw0 = n0 & (HW - 1);

    // ---- stage x: thread t handles point p, channel half cg (32 ch) ----
    {
        const int p = t & 127, cg = t >> 7;
        const float* xp = x + ((size_t)b * CDIM + cg * 32) * HW + hw0 + p;
        float xs = 0.0f;
        #pragma unroll
        for (int j = 0; j < 32; j += 2) {
            float v0 = xp[(size_t)j * HW];
            float v1 = xp[(size_t)(j + 1) * HW];
            xs = fmaf(v0, v0, xs);
            xs = fmaf(v1, v1, xs);
            unsigned pk = (unsigned)f2bf(-2.0f * v0) | ((unsigned)f2bf(-2.0f * v1) << 16);
            *(unsigned*)&abf[p * 72 + cg * 32 + j] = pk;
        }
        xsqp[cg * 128 + p] = xs;
    }
    __syncthreads();

    const int l = t & 63, w = t >> 6;
    const int col = l & 15, q = l >> 4;

    // ---- A fragments: wave w owns points w*32..w*32+31 (2 m-tiles) ----
    short8 a[2][2];
    #pragma unroll
    for (int mt = 0; mt < 2; ++mt)
        #pragma unroll
        for (int f = 0; f < 2; ++f)
            a[mt][f] = *(const short8*)&abf[(w * 32 + mt * 16 + col) * 72 + f * 32 + q * 8];

    // ---- k-loop: acc = e_sq + (-2x)·e  (C-init carries e_sq) ----
    float bd[8];
    int   bk[8];
    #pragma unroll
    for (int i = 0; i < 8; ++i) { bd[i] = 3.4e38f; bk[i] = 0; }

    const short8* bp = ((const short8*)cbB) + l;
    int cand = col;
    #pragma unroll 4
    for (int kt = 0; kt < 64; ++kt) {
        short8 b0 = bp[kt * 128];
        short8 b1 = bp[kt * 128 + 64];
        float  ev = esq[kt * 16 + col];
        float4v c0 = {ev, ev, ev, ev};
        float4v acc0 = __builtin_amdgcn_mfma_f32_16x16x32_bf16(a[0][0], b0, c0, 0, 0, 0);
        acc0 = __builtin_amdgcn_mfma_f32_16x16x32_bf16(a[0][1], b1, acc0, 0, 0, 0);
        float4v acc1 = __builtin_amdgcn_mfma_f32_16x16x32_bf16(a[1][0], b0, c0, 0, 0, 0);
        acc1 = __builtin_amdgcn_mfma_f32_16x16x32_bf16(a[1][1], b1, acc1, 0, 0, 0);
        #pragma unroll
        for (int r = 0; r < 4; ++r) {
            bool c0b = acc0[r] < bd[r];
            bk[r] = c0b ? cand : bk[r];
            bd[r] = c0b ? acc0[r] : bd[r];
            bool c1b = acc1[r] < bd[4 + r];
            bk[4 + r] = c1b ? cand : bk[4 + r];
            bd[4 + r] = c1b ? acc1[r] : bd[4 + r];
        }
        cand += 16;
    }

    // ---- argmin across the 16 code-columns (shuffle butterfly) ----
    #pragma unroll
    for (int s = 1; s < 16; s <<= 1) {
        #pragma unroll
        for (int i = 0; i < 8; ++i) {
            float od = __shfl_xor(bd[i], s, 64);
            int   ok = __shfl_xor(bk[i], s, 64);
            if (od < bd[i]) { bd[i] = od; bk[i] = ok; }
        }
    }
    if (col == 0) {
        #pragma unroll
        for (int mt = 0; mt < 2; ++mt)
            #pragma unroll
            for (int r = 0; r < 4; ++r) {
                int p = w * 32 + mt * 16 + q * 4 + r;
                dbl[p]  = bd[mt * 4 + r];
                idxl[p] = bk[mt * 4 + r];
            }
    }
    __syncthreads();

    // ---- loss: per-point  x_sq + best(e_sq - 2 dot) ----
    if (t < 128) {
        float lp = dbl[t] + xsqp[t] + xsqp[128 + t];
        #pragma unroll
        for (int off = 32; off > 0; off >>= 1) lp += __shfl_down(lp, off, 64);
        if ((t & 63) == 0) part[t >> 6] = lp;
    }
    __syncthreads();
    if (t == 0) atomicAdd(accum, part[0] + part[1]);

    // ---- z_q: gather winning rows (L1/L2-hot), coalesced strided store ----
    {
        const int p = t & 127, ch = t >> 7;
        const float4v* crow = (const float4v*)(cb + (size_t)idxl[p] * CDIM + ch * 32);
        float* zp = zq + ((size_t)b * CDIM + ch * 32) * HW + hw0 + p;
        #pragma unroll
        for (int i = 0; i < 8; ++i) {
            float4v vv = crow[i];
            zp[(size_t)(i * 4 + 0) * HW] = vv[0];
            zp[(size_t)(i * 4 + 1) * HW] = vv[1];
            zp[(size_t)(i * 4 + 2) * HW] = vv[2];
            zp[(size_t)(i * 4 + 3) * HW] = vv[3];
        }
    }
}

__global__ void vq_final(const float* __restrict__ accum, float* __restrict__ out_loss) {
    float mse = accum[0] * (1.0f / (float)NELM);
    out_loss[0] = 1.25f * mse;
}

extern "C" void kernel_launch(void* const* d_in, const int* in_sizes, int n_in,
                              void* d_out, int out_size, void* d_ws, size_t ws_size,
                              hipStream_t stream) {
    const float* x  = (const float*)d_in[0];
    const float* cb = (const float*)d_in[1];
    float* esq   = (float*)d_ws;                       // 1024 floats
    float* accum = esq + KCB;                          // 1 float
    unsigned short* cbB = (unsigned short*)(esq + 2048); // 64K bf16, 16B-aligned
    float* zq   = (float*)d_out;
    float* loss = zq + NELM;

    vq_prep <<<32,   256, 0, stream>>>(cb, esq, accum, cbB);
    vq_main <<<1024, 256, 0, stream>>>(x, cb, esq, cbB, zq, accum);
    vq_final<<<1,    1,   0, stream>>>(accum, loss);
}